// Round 16
// baseline (1897.878 us; speedup 1.0000x reference)
//
#include <hip/hip_runtime.h>

#define BATCHN 128
#define SEQT   2048
#define FEAT   64
#define UNITS  64
#define NCOL   256   // 4*UNITS gate columns
#define OUTD   6

typedef __fp16 hv2 __attribute__((ext_vector_type(2)));

__device__ __forceinline__ float fast_exp2(float x) {
#if __has_builtin(__builtin_amdgcn_exp2f)
    return __builtin_amdgcn_exp2f(x);
#else
    return exp2f(x);
#endif
}
__device__ __forceinline__ float fast_rcp(float x) {
#if __has_builtin(__builtin_amdgcn_rcpf)
    return __builtin_amdgcn_rcpf(x);
#else
    return 1.0f / x;
#endif
}
__device__ __forceinline__ float sig_(float x) {
    return fast_rcp(1.0f + fast_exp2(-1.4426950408889634f * x));
}
// tanh(x) = 2/(1+e^{-2x}) - 1
__device__ __forceinline__ float tanh_(float x) {
    float e = fast_exp2(-2.8853900817779268f * x);   // e^{-2x}
    return fmaf(2.0f, fast_rcp(1.0f + e), -1.0f);
}

// 2xf16 MAC with f32 accumulate (v_dot2_f32_f16)
__device__ __forceinline__ float fdot2_(hv2 a, hv2 b, float c) {
#if __has_builtin(__builtin_amdgcn_fdot2)
    return __builtin_amdgcn_fdot2(a, b, c, false);
#else
    return fmaf((float)a.x, (float)b.x, fmaf((float)a.y, (float)b.y, c));
#endif
}
__device__ __forceinline__ hv2 cvtpk_(float a, float b) {
    return __builtin_amdgcn_cvt_pkrtz(a, b);
}
// wave-uniform broadcast of lane l's u32 (compile-time l)
__device__ __forceinline__ unsigned int rlane_(unsigned int v, int l) {
    return (unsigned int)__builtin_amdgcn_readlane((int)v, l);
}
// pull f32 from lane (byteaddr/4)
__device__ __forceinline__ float bperm_(int byteaddr, float v) {
    return __builtin_bit_cast(float,
        __builtin_amdgcn_ds_bpermute(byteaddr, __builtin_bit_cast(int, v)));
}

// 6 waves = (layer g, role r): FF_g holds W only, REC_g holds U only
// (128 weight VGPRs each). launch_bounds(384,1): VGPR cap 256 -> ~170 regs
// allocate with ZERO spill (R15's cap of 128 forced scratch spill; that was
// the 2x). Lane u owns unit u's 4 gate cols over full K=64: dot completes
// in-lane. Operand broadcast via v_readlane of packed f16x2. REC keeps h as
// register state (2x ds_bpermute repack). FF->REC handoff: z_ff float4 via
// LDS, read issued EARLY and added at chain END (off the dependency head).
// 6-stage skew (alpha=2g+r), 1 lgkm-only barrier/tick.
__global__ __launch_bounds__(384, 1)
void lstm3_ffrec2(const float* __restrict__ x,
                  const float* __restrict__ W0, const float* __restrict__ U0,
                  const float* __restrict__ b0,
                  const float* __restrict__ W1, const float* __restrict__ U1,
                  const float* __restrict__ b1,
                  const float* __restrict__ Wf, const float* __restrict__ bfv,
                  const float* __restrict__ Wo, const float* __restrict__ bov,
                  float* __restrict__ out)
{
    const int b   = blockIdx.x;
    const int tid = threadIdx.x;   // 0..383
    const int wid = tid >> 6;      // 0..5
    const int g   = wid >> 1;      // layer 0,1,2
    const int r   = wid & 1;       // 0=FF (W), 1=REC (U + activations)
    const int u   = tid & 63;      // unit/lane
    const int j32 = u & 31;

    __shared__ unsigned int lhp[3][2][32];               // packed h pairs
    __shared__ __align__(16) float lzf[3][2][UNITS][4];  // z_ff float4
    __shared__ float lh2f[UNITS];
    __shared__ float lact[UNITS];

    // ---- weights: 4 cols x 64 k of ONE matrix, f16 k-pairs (128 VGPRs) ----
    const float* M = (g == 0) ? ((r == 0) ? W0 : U0) : ((r == 0) ? W1 : U1);
    const float* bsel = (g == 0) ? b0 : b1;

    hv2 wM[32][4];
    float biasv[4];
#pragma unroll
    for (int gg = 0; gg < 4; ++gg) {
        const int col = (gg << 6) + u;
#pragma unroll
        for (int j = 0; j < 32; ++j) {
            hv2 w;
            w.x = (__fp16)M[(2 * j) * NCOL + col];
            w.y = (__fp16)M[(2 * j + 1) * NCOL + col];
            wM[j][gg] = w;
        }
        biasv[gg] = bsel[col];   // only FF adds it
    }

    // zero handoff buffers
    if (tid < 192) ((unsigned int*)lhp)[tid] = 0u;
    for (int i = tid; i < 3 * 2 * UNITS * 4; i += 384) ((float*)lzf)[i] = 0.f;

    // x: wave 0 (FF_0), lanes<32 stream pairs (x[t][2u], x[t][2u+1])
    const float2* x2 = (const float2*)(x + (size_t)b * SEQT * FEAT);
    float2 xrA = {0.f, 0.f}, xrB = {0.f, 0.f};
    if (wid == 0 && u < 32) {
        xrA = x2[0 * 32 + u];    // x(0)
        xrB = x2[1 * 32 + u];    // x(1)
    }
    __syncthreads();

    const int alpha = 2 * g + r;
    float c = 0.f, h = 0.f;
    unsigned int rpk = 0u;       // REC: own h(t-1) packed (lane j<32 = pair j)

#define TICK(TK, XR)                                                          \
    {                                                                         \
        const int t_ = (TK) - alpha;                                          \
        const float2 xcur = XR;                                               \
        if (wid == 0 && u < 32) {   /* refill with x(TK+2) */                 \
            int tn = (TK) + 2; if (tn > SEQT - 1) tn = SEQT - 1;              \
            XR = x2[(size_t)tn * 32 + u];                                     \
        }                                                                     \
        if (t_ >= 0 && t_ < SEQT) {                                           \
            const int p_ = t_ & 1;                                            \
            unsigned int srcpk;                                               \
            float4 zin = {0.f, 0.f, 0.f, 0.f};                                \
            if (r == 0) {                                                     \
                srcpk = (g == 0) ? __builtin_bit_cast(unsigned int,           \
                                                      cvtpk_(xcur.x, xcur.y)) \
                                 : lhp[g - 1][p_][j32];    /* 1 b32 */        \
            } else {                                                          \
                srcpk = rpk;                                                  \
                zin = *(const float4*)&lzf[g][p_][u][0];   /* issue early */  \
            }                                                                 \
            float aA0 = 0.f, aA1 = 0.f, aA2 = 0.f, aA3 = 0.f;                 \
            float aB0 = 0.f, aB1 = 0.f, aB2 = 0.f, aB3 = 0.f;                 \
            _Pragma("unroll")                                                 \
            for (int j = 0; j < 32; j += 2) {                                 \
                hv2 p0 = __builtin_bit_cast(hv2, rlane_(srcpk, j));           \
                hv2 p1 = __builtin_bit_cast(hv2, rlane_(srcpk, j + 1));       \
                aA0 = fdot2_(p0, wM[j][0], aA0);                              \
                aA1 = fdot2_(p0, wM[j][1], aA1);                              \
                aA2 = fdot2_(p0, wM[j][2], aA2);                              \
                aA3 = fdot2_(p0, wM[j][3], aA3);                              \
                aB0 = fdot2_(p1, wM[j + 1][0], aB0);                          \
                aB1 = fdot2_(p1, wM[j + 1][1], aB1);                          \
                aB2 = fdot2_(p1, wM[j + 1][2], aB2);                          \
                aB3 = fdot2_(p1, wM[j + 1][3], aB3);                          \
            }                                                                 \
            if (r == 0) {            /* publish z_ff(t) (+bias here) */       \
                float4 z4 = {aA0 + aB0 + biasv[0], aA1 + aB1 + biasv[1],      \
                             aA2 + aB2 + biasv[2], aA3 + aB3 + biasv[3]};     \
                *(float4*)&lzf[g][p_][u][0] = z4;                             \
            } else {                 /* gates: zin lands at chain END */      \
                const float zi = aA0 + aB0 + zin.x;                           \
                const float zf = aA1 + aB1 + zin.y;                           \
                const float zg = aA2 + aB2 + zin.z;                           \
                const float zo = aA3 + aB3 + zin.w;                           \
                const float ig = sig_(zi), fg = sig_(zf);                     \
                const float gv = tanh_(zg), og = sig_(zo);                    \
                c = fg * c + ig * gv;                                         \
                h = og * tanh_(c);                                            \
                const float h0 = bperm_(j32 * 8,     h);                      \
                const float h1 = bperm_(j32 * 8 + 4, h);                      \
                rpk = __builtin_bit_cast(unsigned int, cvtpk_(h0, h1));       \
                if (u < 32) lhp[g][p_][u] = rpk;                              \
                if (g == 2 && t_ == SEQT - 1) lh2f[u] = h;                    \
            }                                                                 \
        }                                                                     \
        asm volatile("s_waitcnt lgkmcnt(0)\n\ts_barrier" ::: "memory");       \
    }

    for (int tk = 0; tk < SEQT + 6; tk += 2) {
        TICK(tk,     xrA)
        TICK(tk + 1, xrB)
    }
#undef TICK

    __syncthreads();

    // ---- dense head on final h2 (f32) ----
    if (tid < UNITS) {
        float a = bfv[tid];
#pragma unroll
        for (int k = 0; k < UNITS; ++k) a += lh2f[k] * Wf[k * 64 + tid];
        lact[tid] = fmaxf(a, 0.f);
    }
    __syncthreads();
    if (tid < OUTD) {
        float a = bov[tid];
#pragma unroll
        for (int k = 0; k < UNITS; ++k) a += lact[k] * Wo[k * OUTD + tid];
        out[b * OUTD + tid] = a;
    }
}

extern "C" void kernel_launch(void* const* d_in, const int* in_sizes, int n_in,
                              void* d_out, int out_size, void* d_ws, size_t ws_size,
                              hipStream_t stream) {
    const float* x   = (const float*)d_in[0];
    const float* W0  = (const float*)d_in[1];
    const float* U0  = (const float*)d_in[2];
    const float* b0  = (const float*)d_in[3];
    const float* W1  = (const float*)d_in[4];
    const float* U1  = (const float*)d_in[5];
    const float* b1  = (const float*)d_in[6];
    const float* Wf  = (const float*)d_in[7];
    const float* bfv = (const float*)d_in[8];
    const float* Wo  = (const float*)d_in[9];
    const float* bov = (const float*)d_in[10];
    float* out = (float*)d_out;

    lstm3_ffrec2<<<BATCHN, 384, 0, stream>>>(x, W0, U0, b0, W1, U1, b1,
                                             Wf, bfv, Wo, bov, out);
}